// Round 1
// baseline (298.174 us; speedup 1.0000x reference)
//
#include <hip/hip_runtime.h>
#include <hip/hip_bf16.h>

// Problem constants (from reference): B=4, G=3, p=16, N=256, C=768, H=12, D=64
#define Bc 4
#define Gc 3
#define Pc 16
#define Nc 256
#define Cc_ 768
#define Hc 12
#define Dc 64
#define Mrows (Bc*Gc*Nc)      // 3072 tokens
#define KVcols (2*Cc_)        // 1536

// ---------------------------------------------------------------------------
// Tiled fp32 GEMM:  C[m][n] = sum_k A[m][k] * W[n][k]  (+ bias[n])
// A: (M,K) row-major, W: (N,K) row-major (i.e. torch Linear weight), C: (M,N)
// 64x64 tile, 256 threads, each thread 4x4 micro-tile, K-step 16.
// LDS stored k-major ([k][m]) so compute reads are float4 along m/n.
// ---------------------------------------------------------------------------
__global__ __launch_bounds__(256) void gemm_nt_64(
    const float* __restrict__ A, const float* __restrict__ W,
    float* __restrict__ C, const float* __restrict__ bias,
    int M, int Nn, int K)
{
    __shared__ float As[16][68];   // [k][m], pad keeps float4 alignment, 2-way max
    __shared__ float Bs[16][68];   // [k][n]

    const int tid  = threadIdx.x;
    const int m0   = blockIdx.y << 6;
    const int n0   = blockIdx.x << 6;
    const int tx   = tid & 15;          // n sub-tile
    const int ty   = tid >> 4;          // m sub-tile
    const int lrow = tid >> 2;          // 0..63 (row loaded by this thread)
    const int lk4  = (tid & 3) << 2;    // 0,4,8,12 (k offset)

    const float* Ap = A + (size_t)(m0 + lrow) * K + lk4;
    const float* Wp = W + (size_t)(n0 + lrow) * K + lk4;

    float acc[4][4] = {};

    for (int k0 = 0; k0 < K; k0 += 16) {
        const float4 av = *(const float4*)(Ap + k0);
        const float4 bv = *(const float4*)(Wp + k0);
        __syncthreads();   // previous iteration's LDS reads done
        As[lk4+0][lrow] = av.x; As[lk4+1][lrow] = av.y;
        As[lk4+2][lrow] = av.z; As[lk4+3][lrow] = av.w;
        Bs[lk4+0][lrow] = bv.x; Bs[lk4+1][lrow] = bv.y;
        Bs[lk4+2][lrow] = bv.z; Bs[lk4+3][lrow] = bv.w;
        __syncthreads();
        #pragma unroll
        for (int kk = 0; kk < 16; ++kk) {
            const float4 a4 = *(const float4*)&As[kk][ty << 2];
            const float4 b4 = *(const float4*)&Bs[kk][tx << 2];
            const float a[4] = {a4.x, a4.y, a4.z, a4.w};
            const float b[4] = {b4.x, b4.y, b4.z, b4.w};
            #pragma unroll
            for (int i = 0; i < 4; ++i)
                #pragma unroll
                for (int j = 0; j < 4; ++j)
                    acc[i][j] = fmaf(a[i], b[j], acc[i][j]);
        }
    }

    float bb[4] = {0.f, 0.f, 0.f, 0.f};
    if (bias) {
        const float4 b4 = *(const float4*)&bias[n0 + (tx << 2)];
        bb[0] = b4.x; bb[1] = b4.y; bb[2] = b4.z; bb[3] = b4.w;
    }
    #pragma unroll
    for (int i = 0; i < 4; ++i) {
        const int mrow = m0 + (ty << 2) + i;
        float4 r;
        r.x = acc[i][0] + bb[0];
        r.y = acc[i][1] + bb[1];
        r.z = acc[i][2] + bb[2];
        r.w = acc[i][3] + bb[3];
        *(float4*)&C[(size_t)mrow * Nn + n0 + (tx << 2)] = r;
    }
}

// ---------------------------------------------------------------------------
// Attention: one block (256 thr = 4 waves) per token t = (g*B+b)*N + n.
// Each wave handles heads {w, w+4, w+8}. Per head:
//   scores: lane = (j = lane&31, dhalf = lane>>5), partial dot over 32 dims,
//           combine with shfl_xor(32); softmax via shfl reduction.
//   PV:     lane = output dim d (0..63), p[j] broadcast via shfl.
// K/V are gathered from the per-token KV projection via the triplane index map.
// ---------------------------------------------------------------------------
__global__ __launch_bounds__(256) void attn_kernel(
    const float* __restrict__ Q,    // (Mrows, C) in x-order rows (b,g,n)
    const float* __restrict__ KV,   // (Mrows, 2C) in x-order rows; [0,C)=k, [C,2C)=v
    float* __restrict__ Oa)         // (Mrows, C) in out-order rows (g,b,n)
{
    const int t  = blockIdx.x;          // (g*4 + b)*256 + n
    const int g  = t >> 10;
    const int b  = (t >> 8) & 3;
    const int n  = t & 255;
    const int a  = n >> 4;
    const int bc = n & 15;

    __shared__ float qs[Cc_];
    __shared__ int   rows[32];

    const int qrow = (b * Gc + g) * Nc + n;   // x-order row of this token
    for (int i = threadIdx.x; i < Cc_; i += 256)
        qs[i] = Q[(size_t)qrow * Cc_ + i];

    if (threadIdx.x < 32) {
        const int j = threadIdx.x;
        int g1 = g + 1; if (g1 >= 3) g1 -= 3;
        int g2 = g + 2; if (g2 >= 3) g2 -= 3;
        rows[j] = (j < 16) ? ((b * Gc + g1) * Nc + a * 16 + j)
                           : ((b * Gc + g2) * Nc + (j - 16) * 16 + bc);
    }
    __syncthreads();

    const int wave = threadIdx.x >> 6;
    const int lane = threadIdx.x & 63;
    const int j    = lane & 31;
    const int dh   = lane >> 5;
    const size_t kvrow = (size_t)rows[j] * KVcols;

    for (int hh = 0; hh < 3; ++hh) {
        const int h = wave + hh * 4;          // heads 0..11
        // ---- scores ----
        const float* kp = KV + kvrow + h * Dc + dh * 32;
        const float* qp = qs + h * Dc + dh * 32;
        float s = 0.f;
        #pragma unroll
        for (int dd = 0; dd < 32; ++dd) s = fmaf(qp[dd], kp[dd], s);
        s += __shfl_xor(s, 32);               // full 64-dim dot (dup in halves)
        s *= 0.125f;                          // 1/sqrt(64)

        // ---- softmax over 32 ctx (halves hold identical values) ----
        float m = s;
        #pragma unroll
        for (int off = 16; off >= 1; off >>= 1) m = fmaxf(m, __shfl_xor(m, off));
        const float e = __expf(s - m);
        float l = e;
        #pragma unroll
        for (int off = 16; off >= 1; off >>= 1) l += __shfl_xor(l, off);
        const float pr = e / l;

        // ---- PV: lane = output dim ----
        float o = 0.f;
        #pragma unroll 8
        for (int jj = 0; jj < 32; ++jj) {
            const float pj = __shfl(pr, jj);  // p[jj] lives on lane jj
            const int rr = rows[jj];
            o = fmaf(pj, KV[(size_t)rr * KVcols + Cc_ + h * Dc + lane], o);
        }
        Oa[(size_t)t * Cc_ + h * Dc + lane] = o;
    }
}

extern "C" void kernel_launch(void* const* d_in, const int* in_sizes, int n_in,
                              void* d_out, int out_size, void* d_ws, size_t ws_size,
                              hipStream_t stream) {
    const float* x   = (const float*)d_in[0];   // (B,G,N,C)
    const float* wq  = (const float*)d_in[1];   // (C,C)
    const float* wkv = (const float*)d_in[2];   // (2C,C)
    const float* pw  = (const float*)d_in[3];   // (C,C)
    const float* pb  = (const float*)d_in[4];   // (C,)
    float* out = (float*)d_out;

    float* Q   = (float*)d_ws;                  // 3072*768
    float* KV  = Q  + (size_t)Mrows * Cc_;      // 3072*1536
    float* ATT = KV + (size_t)Mrows * KVcols;   // 3072*768

    const dim3 blk(256);

    // Q = x @ wq^T      (x-order rows)
    gemm_nt_64<<<dim3(Cc_ / 64, Mrows / 64), blk, 0, stream>>>(
        x, wq, Q, nullptr, Mrows, Cc_, Cc_);
    // KV = x @ w_kv^T   (x-order rows) — projects each token ONCE (32x less
    // work than projecting the materialized context)
    gemm_nt_64<<<dim3(KVcols / 64, Mrows / 64), blk, 0, stream>>>(
        x, wkv, KV, nullptr, Mrows, KVcols, Cc_);
    // attention with gathered K/V, writes out-order rows
    attn_kernel<<<dim3(Mrows), blk, 0, stream>>>(Q, KV, ATT);
    // out = ATT @ proj_w^T + proj_b   (d_out layout == flat (g,b,n,c))
    gemm_nt_64<<<dim3(Cc_ / 64, Mrows / 64), blk, 0, stream>>>(
        ATT, pw, out, pb, Mrows, Cc_, Cc_);
}